// Round 2
// baseline (780.496 us; speedup 1.0000x reference)
//
#include <hip/hip_runtime.h>
#include <hip/hip_bf16.h>
#include <math.h>

// Problem constants
#define HH 80
#define WW 80
#define NPIX 6400          // H*W
#define CC 36              // 6 labels x 6 channels, batched
#define NC 6
#define NUM_ITER 5
#define TJ 128             // j-tile staged in LDS (supports js in {50,25,10})

typedef __attribute__((ext_vector_type(2))) float f32x2;

// exp2 coefficients: exp(-d/(2*theta^2)) = exp2(C*d)
// alpha=8 -> 2*64=128 ; beta=.15 -> 2*.0225=.045 ; gamma=3 -> 2*9=18
#define LN2 0.6931471805599453
__device__ __constant__ const float kCg = (float)(-1.0 / (18.0 * LN2));
// pre-scales so that w = exp2(-(dy_s^2+dx_s^2+d0_s^2+d1_s^2+d2_s^2))
__device__ __constant__ const float kSA = (float)(0.08838834764831845);   // sqrt(1/(128*ln2))
__device__ __constant__ const float kSB = (float)(5.663898078577187);    // sqrt(1/(0.045*ln2))

// ---------------------------------------------------------------------------
// init: q[n][l*6+c] = unary[n][c]; norm_s[n] = analytic separable row-sum
// ---------------------------------------------------------------------------
__global__ __launch_bounds__(256) void k_init(const float* __restrict__ unary,
                                              float* __restrict__ q,
                                              float* __restrict__ norm_s) {
    int i = blockIdx.x * 256 + threadIdx.x;
    if (i >= NPIX) return;
    int y = i / WW, x = i - y * WW;
    float Sy = 0.f, Sx = 0.f;
    for (int t = 0; t < 80; t++) {
        float dy = (float)(y - t), dx = (float)(x - t);
        Sy += __builtin_amdgcn_exp2f(kCg * dy * dy);
        Sx += __builtin_amdgcn_exp2f(kCg * dx * dx);
    }
    norm_s[i] = Sy * Sx;
    float u[NC];
#pragma unroll
    for (int c = 0; c < NC; c++) u[c] = unary[i * NC + c];
#pragma unroll
    for (int l = 0; l < NC; l++)
#pragma unroll
        for (int c = 0; c < NC; c++) q[i * CC + l * NC + c] = u[c];
}

// ---------------------------------------------------------------------------
// softmax over channels for each (pixel, label)
// ---------------------------------------------------------------------------
__global__ __launch_bounds__(256) void k_softmax(const float* __restrict__ q,
                                                 float* __restrict__ sm) {
    int t = blockIdx.x * 256 + threadIdx.x;  // t = n*6 + l
    if (t >= NPIX * NC) return;
    const float* qp = q + (size_t)t * NC;
    float v[NC], mx = -1e30f;
#pragma unroll
    for (int c = 0; c < NC; c++) { v[c] = qp[c]; mx = fmaxf(mx, v[c]); }
    float sum = 0.f;
#pragma unroll
    for (int c = 0; c < NC; c++) { v[c] = __expf(v[c] - mx); sum += v[c]; }
    float inv = 1.f / sum;
    float* sp = sm + (size_t)t * NC;
#pragma unroll
    for (int c = 0; c < NC; c++) sp[c] = v[c] * inv;
}

// ---------------------------------------------------------------------------
// bilateral N^2 pass: part_b[s][i][cc] = sum_{j in slice s} w(i,j)*sm[j][cc]
// ---------------------------------------------------------------------------
template <bool WITH_NORM>
__global__ __launch_bounds__(256) void k_bilateral(const float* __restrict__ sm,
                                                   const float* __restrict__ feat,
                                                   float* __restrict__ part_b,
                                                   float* __restrict__ part_nb,
                                                   int js) {
    __shared__ __align__(16) float4 s_sm4[TJ * 9];
    __shared__ float s_pf[TJ * 5];   // pre-scaled y, x, f0, f1, f2
    int tid = threadIdx.x;
    int i = blockIdx.x * 256 + tid;  // pixel i
    int s = blockIdx.y;              // j-slice
    int slice = NPIX / js;
    int chunks = slice / TJ;

    int yi_i = i / WW;
    float yis = kSA * (float)yi_i;
    float xis = kSA * (float)(i - yi_i * WW);
    float fi0 = kSB * feat[i * 3 + 0];
    float fi1 = kSB * feat[i * 3 + 1];
    float fi2 = kSB * feat[i * 3 + 2];

    f32x2 acc[18];
#pragma unroll
    for (int r = 0; r < 18; r++) acc[r] = (f32x2){0.f, 0.f};
    float wsum = 0.f;

    for (int ch = 0; ch < chunks; ch++) {
        int jbase = s * slice + ch * TJ;
        __syncthreads();  // protect LDS from previous chunk readers
        {
            const float4* src = (const float4*)(sm + (size_t)jbase * CC);
            for (int idx = tid; idx < TJ * 9; idx += 256) s_sm4[idx] = src[idx];
            for (int idx = tid; idx < TJ; idx += 256) {
                int j = jbase + idx;
                int yj = j / WW;
                s_pf[idx * 5 + 0] = kSA * (float)yj;
                s_pf[idx * 5 + 1] = kSA * (float)(j - yj * WW);
                s_pf[idx * 5 + 2] = kSB * feat[j * 3 + 0];
                s_pf[idx * 5 + 3] = kSB * feat[j * 3 + 1];
                s_pf[idx * 5 + 4] = kSB * feat[j * 3 + 2];
            }
        }
        __syncthreads();

        for (int jj = 0; jj < TJ; jj++) {
            float dy = yis - s_pf[jj * 5 + 0];
            float dx = xis - s_pf[jj * 5 + 1];
            float d0 = fi0 - s_pf[jj * 5 + 2];
            float d1 = fi1 - s_pf[jj * 5 + 3];
            float d2 = fi2 - s_pf[jj * 5 + 4];
            float a = dy * dy;
            a = fmaf(dx, dx, a);
            a = fmaf(d0, d0, a);
            a = fmaf(d1, d1, a);
            a = fmaf(d2, d2, a);
            float w = __builtin_amdgcn_exp2f(-a);
            if (WITH_NORM) wsum += w;
            f32x2 ww = {w, w};
            const f32x2* smj = (const f32x2*)(s_sm4 + jj * 9);
#pragma unroll
            for (int r = 0; r < 18; r++) {
                f32x2 v = smj[r];
                asm("v_pk_fma_f32 %0, %1, %2, %0" : "+v"(acc[r]) : "v"(ww), "v"(v));
            }
        }
    }
    f32x2* outp = (f32x2*)(part_b + ((size_t)s * NPIX + i) * CC);
#pragma unroll
    for (int r = 0; r < 18; r++) outp[r] = acc[r];
    if (WITH_NORM) part_nb[(size_t)s * NPIX + i] = wsum;
}

// ---------------------------------------------------------------------------
// exact separable spatial filter (two 80-tap passes)
// ---------------------------------------------------------------------------
__global__ __launch_bounds__(256) void k_convx(const float* __restrict__ in,
                                               float* __restrict__ out) {
    __shared__ float g[80];
    int tid = threadIdx.x;
    if (tid < 80) { float d = (float)tid; g[tid] = __builtin_amdgcn_exp2f(kCg * d * d); }
    __syncthreads();
    int t = blockIdx.x * 256 + tid;  // over NPIX*CC
    if (t >= NPIX * CC) return;
    int cc = t % CC;
    int x = (t / CC) % WW;
    int y = t / (CC * WW);
    const float* row = in + (size_t)(y * WW) * CC + cc;
    float acc = 0.f;
    for (int xp = 0; xp < WW; xp++) acc = fmaf(g[abs(x - xp)], row[(size_t)xp * CC], acc);
    out[t] = acc;
}

__global__ __launch_bounds__(256) void k_convy(const float* __restrict__ in,
                                               float* __restrict__ out) {
    __shared__ float g[80];
    int tid = threadIdx.x;
    if (tid < 80) { float d = (float)tid; g[tid] = __builtin_amdgcn_exp2f(kCg * d * d); }
    __syncthreads();
    int t = blockIdx.x * 256 + tid;
    if (t >= NPIX * CC) return;
    int cc = t % CC;
    int x = (t / CC) % WW;
    int y = t / (CC * WW);
    float acc = 0.f;
    for (int yp = 0; yp < HH; yp++)
        acc = fmaf(g[abs(y - yp)], in[(size_t)(yp * WW + x) * CC + cc], acc);
    out[t] = acc;
}

// ---------------------------------------------------------------------------
// update: reduce part_b slices, message, pairwise, q; stores msg for the ELBO
// NORM variant also reduces part_nb into norm_b (iteration 0 only)
// ---------------------------------------------------------------------------
template <bool NORM>
__global__ __launch_bounds__(256) void k_update(const float* __restrict__ part_b,
                                                const float* __restrict__ part_nb,
                                                const float* __restrict__ filt_s,
                                                const float* __restrict__ norm_s,
                                                float* __restrict__ norm_b,
                                                const float* __restrict__ unary,
                                                const float* __restrict__ SW,
                                                const float* __restrict__ BW,
                                                const float* __restrict__ CM,
                                                const float* __restrict__ LG,
                                                float* __restrict__ q,
                                                float* __restrict__ msg,
                                                int js) {
    __shared__ float sSW[36], sBW[36], sCM[36], sLG[36];
    int tid = threadIdx.x;
    if (tid < 36) { sSW[tid] = SW[tid]; sBW[tid] = BW[tid]; sCM[tid] = CM[tid]; sLG[tid] = LG[tid]; }
    __syncthreads();
    int t = blockIdx.x * 256 + tid;  // t = n*6 + l
    if (t >= NPIX * NC) return;
    int n = t / NC, l = t - n * NC;
    float invs = 1.f / norm_s[n];
    float invb;
    if (NORM) {
        float nb = 0.f;
        for (int s = 0; s < js; s++) nb += part_nb[(size_t)s * NPIX + n];
        norm_b[n] = nb;            // 6 threads write same value - benign
        invb = 1.f / nb;
    } else {
        invb = 1.f / norm_b[n];
    }
    float fs[NC], fb[NC];
#pragma unroll
    for (int c = 0; c < NC; c++) fb[c] = 0.f;
    for (int s = 0; s < js; s++) {
        const float* pp = part_b + ((size_t)s * NPIX + n) * CC + l * NC;
#pragma unroll
        for (int c = 0; c < NC; c++) fb[c] += pp[c];
    }
    const float* fsp = filt_s + (size_t)n * CC + l * NC;
#pragma unroll
    for (int c = 0; c < NC; c++) { fs[c] = fsp[c] * invs; fb[c] *= invb; }
    float m[NC];
#pragma unroll
    for (int c = 0; c < NC; c++) {
        float a = 0.f;
#pragma unroll
        for (int cp = 0; cp < NC; cp++)
            a += sSW[c * NC + cp] * fs[cp] + sBW[c * NC + cp] * fb[cp];
        m[c] = a;
    }
    float* mp = msg + (size_t)n * CC + l * NC;
#pragma unroll
    for (int c = 0; c < NC; c++) mp[c] = m[c];
    float* qp = q + (size_t)n * CC + l * NC;
    const float* up = unary + (size_t)n * NC;
#pragma unroll
    for (int c = 0; c < NC; c++) {
        float pw = 0.f;
#pragma unroll
        for (int cp = 0; cp < NC; cp++) pw += sCM[c * NC + cp] * m[cp];
        qp[c] = up[c] + sLG[c * NC + l] - pw;
    }
}

// ---------------------------------------------------------------------------
// ELBO: out[l] = sum_{n,c} sm*(unary + LG - ln(sm+1e-10) - msg)
// ---------------------------------------------------------------------------
__global__ __launch_bounds__(256) void k_elbo(const float* __restrict__ sm,
                                              const float* __restrict__ msg,
                                              const float* __restrict__ unary,
                                              const float* __restrict__ LG,
                                              float* __restrict__ out) {
    __shared__ float red[256];
    int l = blockIdx.y;
    int n = blockIdx.x * 256 + threadIdx.x;
    float v = 0.f;
    if (n < NPIX) {
        const float* sp = sm + (size_t)n * CC + l * NC;
        const float* mp = msg + (size_t)n * CC + l * NC;
        const float* up = unary + (size_t)n * NC;
#pragma unroll
        for (int c = 0; c < NC; c++) {
            float s = sp[c];
            v += s * (up[c] + LG[c * NC + l] - logf(s + 1e-10f) - mp[c]);
        }
    }
    red[threadIdx.x] = v;
    __syncthreads();
    for (int off = 128; off > 0; off >>= 1) {
        if (threadIdx.x < off) red[threadIdx.x] += red[threadIdx.x + off];
        __syncthreads();
    }
    if (threadIdx.x == 0) atomicAdd(&out[l], red[0]);
}

// ---------------------------------------------------------------------------
extern "C" void kernel_launch(void* const* d_in, const int* in_sizes, int n_in,
                              void* d_out, int out_size, void* d_ws, size_t ws_size,
                              hipStream_t stream) {
    const float* unary = (const float*)d_in[0];  // [N][6]
    const float* feat  = (const float*)d_in[1];  // [N][3]
    const float* CM    = (const float*)d_in[2];  // [6][6]
    const float* LG    = (const float*)d_in[3];
    const float* SW    = (const float*)d_in[4];
    const float* BW    = (const float*)d_in[5];
    float* out = (float*)d_out;

    // choose j-slice count from available scratch (deterministic per call)
    const size_t fixed_f = (size_t)2 * NPIX + (size_t)5 * NPIX * CC;
    int js = 50;
    if (ws_size < (fixed_f + (size_t)js * NPIX * (CC + 1)) * 4) js = 25;
    if (ws_size < (fixed_f + (size_t)js * NPIX * (CC + 1)) * 4) js = 10;

    float* ws = (float*)d_ws;
    float* norm_s  = ws;                      // N
    float* norm_b  = norm_s + NPIX;           // N
    float* q       = norm_b + NPIX;           // N*36
    float* sm      = q + (size_t)NPIX * CC;   // N*36
    float* tmpx    = sm + (size_t)NPIX * CC;  // N*36
    float* filt_s  = tmpx + (size_t)NPIX * CC;
    float* msg     = filt_s + (size_t)NPIX * CC;
    float* part_nb = msg + (size_t)NPIX * CC;          // js*N
    float* part_b  = part_nb + (size_t)js * NPIX;      // js*N*36

    k_init<<<25, 256, 0, stream>>>(unary, q, norm_s);

    for (int it = 0; it < NUM_ITER; it++) {
        k_softmax<<<150, 256, 0, stream>>>(q, sm);
        if (it == 0)
            k_bilateral<true><<<dim3(25, js), 256, 0, stream>>>(sm, feat, part_b, part_nb, js);
        else
            k_bilateral<false><<<dim3(25, js), 256, 0, stream>>>(sm, feat, part_b, part_nb, js);
        k_convx<<<900, 256, 0, stream>>>(sm, tmpx);
        k_convy<<<900, 256, 0, stream>>>(tmpx, filt_s);
        if (it == 0)
            k_update<true><<<150, 256, 0, stream>>>(part_b, part_nb, filt_s, norm_s, norm_b,
                                                    unary, SW, BW, CM, LG, q, msg, js);
        else
            k_update<false><<<150, 256, 0, stream>>>(part_b, part_nb, filt_s, norm_s, norm_b,
                                                     unary, SW, BW, CM, LG, q, msg, js);
    }

    hipMemsetAsync(out, 0, out_size * sizeof(float), stream);
    k_elbo<<<dim3(25, NC), 256, 0, stream>>>(sm, msg, unary, LG, out);
}

// Round 3
// 610.365 us; speedup vs baseline: 1.2787x; 1.2787x over previous
//
#include <hip/hip_runtime.h>
#include <hip/hip_bf16.h>
#include <math.h>

// Problem constants
#define HH 80
#define WW 80
#define NPIX 6400          // H*W
#define CC 36              // 6 labels x 6 channels, batched
#define NC 6
#define NUM_ITER 5
#define LN2 0.6931471805599453

// exp(-d/(2*theta^2)) = exp2(C*d): gamma=3 -> 2*9=18
__device__ __constant__ const float kCg = (float)(-1.0 / (18.0 * LN2));
// pre-scales so that w = exp2(-(dy^2+dx^2+d0^2+d1^2+d2^2)) in scaled coords
__device__ __constant__ const float kSA = 0.08838834764831845f;  // sqrt(1/(128*ln2))
__device__ __constant__ const float kSB = 5.663898078577187f;    // sqrt(1/(0.045*ln2))

// ---------------------------------------------------------------------------
// init: norm_s analytic; pf[n][8] = prescaled (y,x,f0,f1,f2); sm0 = softmax(unary)
// ---------------------------------------------------------------------------
__global__ __launch_bounds__(256) void k_init(const float* __restrict__ unary,
                                              const float* __restrict__ feat,
                                              float* __restrict__ sm,
                                              float* __restrict__ pf,
                                              float* __restrict__ norm_s) {
    int i = blockIdx.x * 256 + threadIdx.x;
    if (i >= NPIX) return;
    int y = i / WW, x = i - y * WW;
    float Sy = 0.f, Sx = 0.f;
    for (int t = 0; t < 80; t++) {
        float dy = (float)(y - t), dx = (float)(x - t);
        Sy += __builtin_amdgcn_exp2f(kCg * dy * dy);
        Sx += __builtin_amdgcn_exp2f(kCg * dx * dx);
    }
    norm_s[i] = Sy * Sx;
    pf[i * 8 + 0] = kSA * (float)y;
    pf[i * 8 + 1] = kSA * (float)x;
    pf[i * 8 + 2] = kSB * feat[i * 3 + 0];
    pf[i * 8 + 3] = kSB * feat[i * 3 + 1];
    pf[i * 8 + 4] = kSB * feat[i * 3 + 2];
    pf[i * 8 + 5] = 0.f; pf[i * 8 + 6] = 0.f; pf[i * 8 + 7] = 0.f;
    float v[NC], mx = -1e30f;
#pragma unroll
    for (int c = 0; c < NC; c++) { v[c] = unary[i * NC + c]; mx = fmaxf(mx, v[c]); }
    float sum = 0.f;
#pragma unroll
    for (int c = 0; c < NC; c++) { v[c] = __expf(v[c] - mx); sum += v[c]; }
    float inv = 1.f / sum;
#pragma unroll
    for (int l = 0; l < NC; l++)
#pragma unroll
        for (int c = 0; c < NC; c++) sm[i * CC + l * NC + c] = v[c] * inv;
}

// ---------------------------------------------------------------------------
// fused: bilateral N^2 slices (blocks 0..bilblocks) + spatial conv-x (900 blocks)
// j-side values are wave-uniform -> scalar loads, no LDS in the bilateral loop.
// ---------------------------------------------------------------------------
template <bool WITH_NORM>
__global__ __launch_bounds__(256) void k_bil_convx(const float* __restrict__ sm,
                                                   const float* __restrict__ pf,
                                                   float* __restrict__ part_b,
                                                   float* __restrict__ part_nb,
                                                   float* __restrict__ tmpx,
                                                   int js, int bilblocks) {
    __shared__ float g[80];
    int tid = threadIdx.x;
    int bid = blockIdx.x;
    if (bid < bilblocks) {
        int s = bid / 25;
        int i = (bid - s * 25) * 256 + tid;  // pixel i (exactly 6400 per slice)
        int slice = NPIX / js;
        int j0 = s * slice;

        float yis = pf[i * 8 + 0];
        float xis = pf[i * 8 + 1];
        float fi0 = pf[i * 8 + 2];
        float fi1 = pf[i * 8 + 3];
        float fi2 = pf[i * 8 + 4];

        float acc[CC];
#pragma unroll
        for (int r = 0; r < CC; r++) acc[r] = 0.f;
        float wsum = 0.f;

        for (int jj = 0; jj < slice; jj++) {
            int j = j0 + jj;
            const float* __restrict__ pj = pf + (size_t)j * 8;   // uniform -> s_load
            float dy = yis - pj[0];
            float dx = xis - pj[1];
            float d0 = fi0 - pj[2];
            float d1 = fi1 - pj[3];
            float d2 = fi2 - pj[4];
            float a = dy * dy;
            a = fmaf(dx, dx, a);
            a = fmaf(d0, d0, a);
            a = fmaf(d1, d1, a);
            a = fmaf(d2, d2, a);
            float w = __builtin_amdgcn_exp2f(-a);
            if (WITH_NORM) wsum += w;
            const float* __restrict__ smj = sm + (size_t)j * CC; // uniform -> s_load
#pragma unroll
            for (int r = 0; r < CC; r++) acc[r] = fmaf(w, smj[r], acc[r]);
        }
        float4* outp = (float4*)(part_b + ((size_t)s * NPIX + i) * CC);
#pragma unroll
        for (int r = 0; r < 9; r++)
            outp[r] = make_float4(acc[4 * r], acc[4 * r + 1], acc[4 * r + 2], acc[4 * r + 3]);
        if (WITH_NORM) part_nb[(size_t)s * NPIX + i] = wsum;
    } else {
        if (tid < 80) { float d = (float)tid; g[tid] = __builtin_amdgcn_exp2f(kCg * d * d); }
        __syncthreads();
        int t = (bid - bilblocks) * 256 + tid;  // exactly NPIX*CC = 900*256
        int cc = t % CC;
        int x = (t / CC) % WW;
        int y = t / (CC * WW);
        const float* row = sm + (size_t)(y * WW) * CC + cc;
        float a = 0.f;
        for (int xp = 0; xp < WW; xp++) a = fmaf(g[abs(x - xp)], row[(size_t)xp * CC], a);
        tmpx[t] = a;
    }
}

// ---------------------------------------------------------------------------
// spatial conv-y (second separable pass)
// ---------------------------------------------------------------------------
__global__ __launch_bounds__(256) void k_convy(const float* __restrict__ in,
                                               float* __restrict__ out) {
    __shared__ float g[80];
    int tid = threadIdx.x;
    if (tid < 80) { float d = (float)tid; g[tid] = __builtin_amdgcn_exp2f(kCg * d * d); }
    __syncthreads();
    int t = blockIdx.x * 256 + tid;
    int cc = t % CC;
    int x = (t / CC) % WW;
    int y = t / (CC * WW);
    float a = 0.f;
    for (int yp = 0; yp < HH; yp++)
        a = fmaf(g[abs(y - yp)], in[(size_t)(yp * WW + x) * CC + cc], a);
    out[t] = a;
}

// ---------------------------------------------------------------------------
// update: reduce part_b, message, pairwise, q, fused softmax -> next sm
// NORM: also reduce part_nb into norm_b. LAST: skip sm write (ELBO needs old sm)
// ---------------------------------------------------------------------------
template <bool NORM, bool LAST>
__global__ __launch_bounds__(256) void k_update(const float* __restrict__ part_b,
                                                const float* __restrict__ part_nb,
                                                const float* __restrict__ filt_s,
                                                const float* __restrict__ norm_s,
                                                float* __restrict__ norm_b,
                                                const float* __restrict__ unary,
                                                const float* __restrict__ SW,
                                                const float* __restrict__ BW,
                                                const float* __restrict__ CM,
                                                const float* __restrict__ LG,
                                                float* __restrict__ sm,
                                                float* __restrict__ msg,
                                                int js) {
    __shared__ float sSW[36], sBW[36], sCM[36], sLG[36];
    int tid = threadIdx.x;
    if (tid < 36) { sSW[tid] = SW[tid]; sBW[tid] = BW[tid]; sCM[tid] = CM[tid]; sLG[tid] = LG[tid]; }
    __syncthreads();
    int t = blockIdx.x * 256 + tid;  // t = n*6 + l
    if (t >= NPIX * NC) return;
    int n = t / NC, l = t - n * NC;
    float invs = 1.f / norm_s[n];
    float invb;
    if (NORM) {
        float nb = 0.f;
        for (int s = 0; s < js; s++) nb += part_nb[(size_t)s * NPIX + n];
        norm_b[n] = nb;  // 6 threads write same value - benign
        invb = 1.f / nb;
    } else {
        invb = 1.f / norm_b[n];
    }
    float fs[NC], fb[NC];
#pragma unroll
    for (int c = 0; c < NC; c++) fb[c] = 0.f;
    for (int s = 0; s < js; s++) {
        const float* pp = part_b + ((size_t)s * NPIX + n) * CC + l * NC;
#pragma unroll
        for (int c = 0; c < NC; c++) fb[c] += pp[c];
    }
    const float* fsp = filt_s + (size_t)n * CC + l * NC;
#pragma unroll
    for (int c = 0; c < NC; c++) { fs[c] = fsp[c] * invs; fb[c] *= invb; }
    float m[NC];
#pragma unroll
    for (int c = 0; c < NC; c++) {
        float a = 0.f;
#pragma unroll
        for (int cp = 0; cp < NC; cp++)
            a += sSW[c * NC + cp] * fs[cp] + sBW[c * NC + cp] * fb[cp];
        m[c] = a;
    }
    float* mp = msg + (size_t)n * CC + l * NC;
#pragma unroll
    for (int c = 0; c < NC; c++) mp[c] = m[c];
    const float* up = unary + (size_t)n * NC;
    float qv[NC], mxq = -1e30f;
#pragma unroll
    for (int c = 0; c < NC; c++) {
        float pw = 0.f;
#pragma unroll
        for (int cp = 0; cp < NC; cp++) pw += sCM[c * NC + cp] * m[cp];
        qv[c] = up[c] + sLG[c * NC + l] - pw;
        mxq = fmaxf(mxq, qv[c]);
    }
    if (!LAST) {
        float e[NC], ssum = 0.f;
#pragma unroll
        for (int c = 0; c < NC; c++) { e[c] = __expf(qv[c] - mxq); ssum += e[c]; }
        float inv = 1.f / ssum;
        float* sp = sm + (size_t)n * CC + l * NC;
#pragma unroll
        for (int c = 0; c < NC; c++) sp[c] = e[c] * inv;
    }
}

// ---------------------------------------------------------------------------
// ELBO: out[l] = sum_{n,c} sm*(unary + LG - ln(sm+1e-10) - msg)
// ---------------------------------------------------------------------------
__global__ __launch_bounds__(256) void k_elbo(const float* __restrict__ sm,
                                              const float* __restrict__ msg,
                                              const float* __restrict__ unary,
                                              const float* __restrict__ LG,
                                              float* __restrict__ out) {
    __shared__ float red[256];
    int l = blockIdx.y;
    int n = blockIdx.x * 256 + threadIdx.x;
    float v = 0.f;
    if (n < NPIX) {
        const float* sp = sm + (size_t)n * CC + l * NC;
        const float* mp = msg + (size_t)n * CC + l * NC;
        const float* up = unary + (size_t)n * NC;
#pragma unroll
        for (int c = 0; c < NC; c++) {
            float s = sp[c];
            v += s * (up[c] + LG[c * NC + l] - logf(s + 1e-10f) - mp[c]);
        }
    }
    red[threadIdx.x] = v;
    __syncthreads();
    for (int off = 128; off > 0; off >>= 1) {
        if (threadIdx.x < off) red[threadIdx.x] += red[threadIdx.x + off];
        __syncthreads();
    }
    if (threadIdx.x == 0) atomicAdd(&out[l], red[0]);
}

// ---------------------------------------------------------------------------
extern "C" void kernel_launch(void* const* d_in, const int* in_sizes, int n_in,
                              void* d_out, int out_size, void* d_ws, size_t ws_size,
                              hipStream_t stream) {
    const float* unary = (const float*)d_in[0];  // [N][6]
    const float* feat  = (const float*)d_in[1];  // [N][3]
    const float* CM    = (const float*)d_in[2];  // [6][6]
    const float* LG    = (const float*)d_in[3];
    const float* SW    = (const float*)d_in[4];
    const float* BW    = (const float*)d_in[5];
    float* out = (float*)d_out;

    // fixed float usage: norm_s,norm_b (2N) + pf (8N) + sm,tmpx,filt_s,msg (144N)
    const size_t fixed_f = (size_t)154 * NPIX;
    int js = 80;
    if (ws_size < (fixed_f + (size_t)js * NPIX * (CC + 1)) * 4) js = 40;
    if (ws_size < (fixed_f + (size_t)js * NPIX * (CC + 1)) * 4) js = 16;
    if (ws_size < (fixed_f + (size_t)js * NPIX * (CC + 1)) * 4) js = 8;

    float* ws = (float*)d_ws;
    float* norm_s  = ws;                        // N
    float* norm_b  = norm_s + NPIX;             // N
    float* pf      = norm_b + NPIX;             // N*8
    float* sm      = pf + (size_t)NPIX * 8;     // N*36
    float* tmpx    = sm + (size_t)NPIX * CC;    // N*36
    float* filt_s  = tmpx + (size_t)NPIX * CC;  // N*36
    float* msg     = filt_s + (size_t)NPIX * CC;// N*36
    float* part_nb = msg + (size_t)NPIX * CC;   // js*N
    float* part_b  = part_nb + (size_t)js * NPIX; // js*N*36

    int bilblocks = 25 * js;

    k_init<<<25, 256, 0, stream>>>(unary, feat, sm, pf, norm_s);

    for (int it = 0; it < NUM_ITER; it++) {
        if (it == 0)
            k_bil_convx<true><<<bilblocks + 900, 256, 0, stream>>>(sm, pf, part_b, part_nb,
                                                                   tmpx, js, bilblocks);
        else
            k_bil_convx<false><<<bilblocks + 900, 256, 0, stream>>>(sm, pf, part_b, part_nb,
                                                                    tmpx, js, bilblocks);
        k_convy<<<900, 256, 0, stream>>>(tmpx, filt_s);
        if (it == 0)
            k_update<true, false><<<150, 256, 0, stream>>>(part_b, part_nb, filt_s, norm_s,
                                                           norm_b, unary, SW, BW, CM, LG,
                                                           sm, msg, js);
        else if (it < NUM_ITER - 1)
            k_update<false, false><<<150, 256, 0, stream>>>(part_b, part_nb, filt_s, norm_s,
                                                            norm_b, unary, SW, BW, CM, LG,
                                                            sm, msg, js);
        else
            k_update<false, true><<<150, 256, 0, stream>>>(part_b, part_nb, filt_s, norm_s,
                                                           norm_b, unary, SW, BW, CM, LG,
                                                           sm, msg, js);
    }

    hipMemsetAsync(out, 0, out_size * sizeof(float), stream);
    k_elbo<<<dim3(25, NC), 256, 0, stream>>>(sm, msg, unary, LG, out);
}

// Round 4
// 331.722 us; speedup vs baseline: 2.3529x; 1.8400x over previous
//
#include <hip/hip_runtime.h>
#include <hip/hip_bf16.h>
#include <math.h>

// Problem constants
#define HH 80
#define WW 80
#define NPIX 6400          // H*W
#define CC 36              // 6 labels x 6 channels, batched
#define CCP 48             // padded channels for MFMA (ch36 = ones -> norm_b)
#define NC 6
#define NUM_ITER 5
#define LN2 0.6931471805599453

typedef __attribute__((ext_vector_type(8))) short bfrag;   // 8 bf16 (4 VGPR)
typedef __attribute__((ext_vector_type(4))) float f32x4;   // MFMA acc

// exp(-d/(2*theta^2)) = exp2(C*d): gamma=3 -> 2*9=18
__device__ __constant__ const float kCg = (float)(-1.0 / (18.0 * LN2));
// pre-scales so that w = exp2(-(dy^2+dx^2+d0^2+d1^2+d2^2)) in scaled coords
__device__ __constant__ const float kSA = 0.08838834764831845f;  // sqrt(1/(128*ln2))
__device__ __constant__ const float kSB = 5.663898078577187f;    // sqrt(1/(0.045*ln2))

__device__ inline unsigned short f2bf(float f) {
    unsigned u = __builtin_bit_cast(unsigned, f);
    unsigned r = (u + 0x7FFFu + ((u >> 16) & 1u)) >> 16;
    return (unsigned short)r;
}

// ---------------------------------------------------------------------------
// init: norm_s analytic; pf SoA prescaled (y,x,f0,f1,f2); sm0 = softmax(unary)
// in fp32 [N][36] and bf16-transposed smbT [48][N] (ch36=1, ch37-47=0)
// ---------------------------------------------------------------------------
__global__ __launch_bounds__(256) void k_init(const float* __restrict__ unary,
                                              const float* __restrict__ feat,
                                              float* __restrict__ sm,
                                              unsigned short* __restrict__ smbT,
                                              float* __restrict__ pf,
                                              float* __restrict__ norm_s) {
    int i = blockIdx.x * 256 + threadIdx.x;
    if (i >= NPIX) return;
    int y = i / WW, x = i - y * WW;
    float Sy = 0.f, Sx = 0.f;
    for (int t = 0; t < 80; t++) {
        float dy = (float)(y - t), dx = (float)(x - t);
        Sy += __builtin_amdgcn_exp2f(kCg * dy * dy);
        Sx += __builtin_amdgcn_exp2f(kCg * dx * dx);
    }
    norm_s[i] = Sy * Sx;
    pf[0 * NPIX + i] = kSA * (float)y;
    pf[1 * NPIX + i] = kSA * (float)x;
    pf[2 * NPIX + i] = kSB * feat[i * 3 + 0];
    pf[3 * NPIX + i] = kSB * feat[i * 3 + 1];
    pf[4 * NPIX + i] = kSB * feat[i * 3 + 2];
    float v[NC], mx = -1e30f;
#pragma unroll
    for (int c = 0; c < NC; c++) { v[c] = unary[i * NC + c]; mx = fmaxf(mx, v[c]); }
    float sum = 0.f;
#pragma unroll
    for (int c = 0; c < NC; c++) { v[c] = __expf(v[c] - mx); sum += v[c]; }
    float inv = 1.f / sum;
#pragma unroll
    for (int l = 0; l < NC; l++)
#pragma unroll
        for (int c = 0; c < NC; c++) {
            float s = v[c] * inv;
            sm[(size_t)i * CC + l * NC + c] = s;
            smbT[(size_t)(l * NC + c) * NPIX + i] = f2bf(s);
        }
    smbT[(size_t)36 * NPIX + i] = 0x3F80;  // bf16(1.0) -> norm channel
#pragma unroll
    for (int cc = 37; cc < CCP; cc++) smbT[(size_t)cc * NPIX + i] = 0;
}

// ---------------------------------------------------------------------------
// fused: MFMA bilateral slices (blocks 0..bilblocks) + spatial conv-x (900)
// Each block: 4 waves; wave owns 2 i-tiles (32 i); loops j over its slice.
// A = W(16i x 32j) computed on the fly in bf16; B = smbT fragments (16B loads)
// part_b[s][i][48] fp32; channel 36 accumulates the bilateral normalizer.
// ---------------------------------------------------------------------------
__global__ __launch_bounds__(256) void k_bil_convx(const unsigned short* __restrict__ smbT,
                                                   const float* __restrict__ pf,
                                                   const float* __restrict__ sm,
                                                   float* __restrict__ part_b,
                                                   float* __restrict__ tmpx,
                                                   int js, int bilblocks) {
    __shared__ float g[80];
    int tid = threadIdx.x;
    int bid = blockIdx.x;
    if (bid < bilblocks) {
        int s = bid / 50, ib = bid - s * 50;
        int slice = NPIX / js;
        int ntiles = slice >> 5;
        int j00 = s * slice;
        int wv = tid >> 6, lane = tid & 63;
        int r = lane & 15, gq = lane >> 4;
        int it0 = ib * 128 + wv * 32;          // first i-tile base
        int iA = it0 + r, iB = iA + 16;

        const float* py = pf + 0 * NPIX;
        const float* px = pf + 1 * NPIX;
        const float* p0 = pf + 2 * NPIX;
        const float* p1 = pf + 3 * NPIX;
        const float* p2 = pf + 4 * NPIX;

        float yA = py[iA], xA = px[iA], fA0 = p0[iA], fA1 = p1[iA], fA2 = p2[iA];
        float yB = py[iB], xB = px[iB], fB0 = p0[iB], fB1 = p1[iB], fB2 = p2[iB];

        f32x4 accA[3], accB[3];
#pragma unroll
        for (int t = 0; t < 3; t++) {
            accA[t] = (f32x4){0.f, 0.f, 0.f, 0.f};
            accB[t] = (f32x4){0.f, 0.f, 0.f, 0.f};
        }

        for (int jt = 0; jt < ntiles; jt++) {
            int jb = j00 + jt * 32 + 8 * gq;   // this lane's k-base (8-aligned)
            f32x4 yj0 = *(const f32x4*)(py + jb), yj1 = *(const f32x4*)(py + jb + 4);
            f32x4 xj0 = *(const f32x4*)(px + jb), xj1 = *(const f32x4*)(px + jb + 4);
            f32x4 c00 = *(const f32x4*)(p0 + jb), c01 = *(const f32x4*)(p0 + jb + 4);
            f32x4 c10 = *(const f32x4*)(p1 + jb), c11 = *(const f32x4*)(p1 + jb + 4);
            f32x4 c20 = *(const f32x4*)(p2 + jb), c21 = *(const f32x4*)(p2 + jb + 4);
            bfrag Bf[3];
#pragma unroll
            for (int t = 0; t < 3; t++)
                Bf[t] = *(const bfrag*)(smbT + (size_t)(16 * t + r) * NPIX + jb);

            float wA[8], wB[8];
#pragma unroll
            for (int e = 0; e < 8; e++) {
                float yj = (e < 4) ? yj0[e & 3] : yj1[e & 3];
                float xj = (e < 4) ? xj0[e & 3] : xj1[e & 3];
                float u0 = (e < 4) ? c00[e & 3] : c01[e & 3];
                float u1 = (e < 4) ? c10[e & 3] : c11[e & 3];
                float u2 = (e < 4) ? c20[e & 3] : c21[e & 3];
                float dy = yA - yj, dx = xA - xj;
                float d0 = fA0 - u0, d1 = fA1 - u1, d2 = fA2 - u2;
                float a = dy * dy;
                a = fmaf(dx, dx, a); a = fmaf(d0, d0, a);
                a = fmaf(d1, d1, a); a = fmaf(d2, d2, a);
                wA[e] = __builtin_amdgcn_exp2f(-a);
                dy = yB - yj; dx = xB - xj;
                d0 = fB0 - u0; d1 = fB1 - u1; d2 = fB2 - u2;
                a = dy * dy;
                a = fmaf(dx, dx, a); a = fmaf(d0, d0, a);
                a = fmaf(d1, d1, a); a = fmaf(d2, d2, a);
                wB[e] = __builtin_amdgcn_exp2f(-a);
            }
            union { unsigned u[4]; bfrag v; } Am, Bm;
#pragma unroll
            for (int m = 0; m < 4; m++) {
                asm("v_cvt_pk_bf16_f32 %0, %1, %2" : "=v"(Am.u[m]) : "v"(wA[2 * m]), "v"(wA[2 * m + 1]));
                asm("v_cvt_pk_bf16_f32 %0, %1, %2" : "=v"(Bm.u[m]) : "v"(wB[2 * m]), "v"(wB[2 * m + 1]));
            }
#pragma unroll
            for (int t = 0; t < 3; t++) {
                accA[t] = __builtin_amdgcn_mfma_f32_16x16x32_bf16(Am.v, Bf[t], accA[t], 0, 0, 0);
                accB[t] = __builtin_amdgcn_mfma_f32_16x16x32_bf16(Bm.v, Bf[t], accB[t], 0, 0, 0);
            }
        }
        // D layout: col = 16t + (lane&15), row = 4*(lane>>4) + reg
#pragma unroll
        for (int t = 0; t < 3; t++)
#pragma unroll
            for (int dreg = 0; dreg < 4; dreg++) {
                int irow = it0 + 4 * gq + dreg;
                part_b[((size_t)s * NPIX + irow) * CCP + 16 * t + r] = accA[t][dreg];
                part_b[((size_t)s * NPIX + irow + 16) * CCP + 16 * t + r] = accB[t][dreg];
            }
    } else {
        if (tid < 80) { float d = (float)tid; g[tid] = __builtin_amdgcn_exp2f(kCg * d * d); }
        __syncthreads();
        int t = (bid - bilblocks) * 256 + tid;  // exactly NPIX*CC = 900*256
        int cc = t % CC;
        int x = (t / CC) % WW;
        int y = t / (CC * WW);
        const float* row = sm + (size_t)(y * WW) * CC + cc;
        float a = 0.f;
        for (int xp = 0; xp < WW; xp++) a = fmaf(g[abs(x - xp)], row[(size_t)xp * CC], a);
        tmpx[t] = a;
    }
}

// ---------------------------------------------------------------------------
// spatial conv-y (second separable pass)
// ---------------------------------------------------------------------------
__global__ __launch_bounds__(256) void k_convy(const float* __restrict__ in,
                                               float* __restrict__ out) {
    __shared__ float g[80];
    int tid = threadIdx.x;
    if (tid < 80) { float d = (float)tid; g[tid] = __builtin_amdgcn_exp2f(kCg * d * d); }
    __syncthreads();
    int t = blockIdx.x * 256 + tid;
    int cc = t % CC;
    int x = (t / CC) % WW;
    int y = t / (CC * WW);
    float a = 0.f;
    for (int yp = 0; yp < HH; yp++)
        a = fmaf(g[abs(y - yp)], in[(size_t)(yp * WW + x) * CC + cc], a);
    out[t] = a;
}

// ---------------------------------------------------------------------------
// update: reduce part_b, message, pairwise, q, fused softmax -> next sm + smbT
// NORM: norm_b from channel 36. LAST: skip sm writes (ELBO needs old sm)
// ---------------------------------------------------------------------------
template <bool NORM, bool LAST>
__global__ __launch_bounds__(256) void k_update(const float* __restrict__ part_b,
                                                const float* __restrict__ filt_s,
                                                const float* __restrict__ norm_s,
                                                float* __restrict__ norm_b,
                                                const float* __restrict__ unary,
                                                const float* __restrict__ SW,
                                                const float* __restrict__ BW,
                                                const float* __restrict__ CM,
                                                const float* __restrict__ LG,
                                                float* __restrict__ sm,
                                                unsigned short* __restrict__ smbT,
                                                float* __restrict__ msg,
                                                int js) {
    __shared__ float sSW[36], sBW[36], sCM[36], sLG[36];
    int tid = threadIdx.x;
    if (tid < 36) { sSW[tid] = SW[tid]; sBW[tid] = BW[tid]; sCM[tid] = CM[tid]; sLG[tid] = LG[tid]; }
    __syncthreads();
    int t = blockIdx.x * 256 + tid;  // t = n*6 + l
    if (t >= NPIX * NC) return;
    int n = t / NC, l = t - n * NC;
    float invs = 1.f / norm_s[n];
    float invb;
    float fb[NC];
#pragma unroll
    for (int c = 0; c < NC; c++) fb[c] = 0.f;
    float nb = 0.f;
    for (int s = 0; s < js; s++) {
        const float* pp = part_b + ((size_t)s * NPIX + n) * CCP;
#pragma unroll
        for (int c = 0; c < NC; c++) fb[c] += pp[l * NC + c];
        if (NORM) nb += pp[36];
    }
    if (NORM) {
        norm_b[n] = nb;  // 6 threads write same value - benign
        invb = 1.f / nb;
    } else {
        invb = 1.f / norm_b[n];
    }
    float fs[NC];
    const float* fsp = filt_s + (size_t)n * CC + l * NC;
#pragma unroll
    for (int c = 0; c < NC; c++) { fs[c] = fsp[c] * invs; fb[c] *= invb; }
    float m[NC];
#pragma unroll
    for (int c = 0; c < NC; c++) {
        float a = 0.f;
#pragma unroll
        for (int cp = 0; cp < NC; cp++)
            a += sSW[c * NC + cp] * fs[cp] + sBW[c * NC + cp] * fb[cp];
        m[c] = a;
    }
    float* mp = msg + (size_t)n * CC + l * NC;
#pragma unroll
    for (int c = 0; c < NC; c++) mp[c] = m[c];
    const float* up = unary + (size_t)n * NC;
    float qv[NC], mxq = -1e30f;
#pragma unroll
    for (int c = 0; c < NC; c++) {
        float pw = 0.f;
#pragma unroll
        for (int cp = 0; cp < NC; cp++) pw += sCM[c * NC + cp] * m[cp];
        qv[c] = up[c] + sLG[c * NC + l] - pw;
        mxq = fmaxf(mxq, qv[c]);
    }
    if (!LAST) {
        float e[NC], ssum = 0.f;
#pragma unroll
        for (int c = 0; c < NC; c++) { e[c] = __expf(qv[c] - mxq); ssum += e[c]; }
        float inv = 1.f / ssum;
        float* sp = sm + (size_t)n * CC + l * NC;
#pragma unroll
        for (int c = 0; c < NC; c++) {
            float sv = e[c] * inv;
            sp[c] = sv;
            smbT[(size_t)(l * NC + c) * NPIX + n] = f2bf(sv);
        }
    }
}

// ---------------------------------------------------------------------------
// ELBO: out[l] = sum_{n,c} sm*(unary + LG - ln(sm+1e-10) - msg)
// ---------------------------------------------------------------------------
__global__ __launch_bounds__(256) void k_elbo(const float* __restrict__ sm,
                                              const float* __restrict__ msg,
                                              const float* __restrict__ unary,
                                              const float* __restrict__ LG,
                                              float* __restrict__ out) {
    __shared__ float red[256];
    int l = blockIdx.y;
    int n = blockIdx.x * 256 + threadIdx.x;
    float v = 0.f;
    if (n < NPIX) {
        const float* sp = sm + (size_t)n * CC + l * NC;
        const float* mp = msg + (size_t)n * CC + l * NC;
        const float* up = unary + (size_t)n * NC;
#pragma unroll
        for (int c = 0; c < NC; c++) {
            float s = sp[c];
            v += s * (up[c] + LG[c * NC + l] - logf(s + 1e-10f) - mp[c]);
        }
    }
    red[threadIdx.x] = v;
    __syncthreads();
    for (int off = 128; off > 0; off >>= 1) {
        if (threadIdx.x < off) red[threadIdx.x] += red[threadIdx.x + off];
        __syncthreads();
    }
    if (threadIdx.x == 0) atomicAdd(&out[l], red[0]);
}

// ---------------------------------------------------------------------------
extern "C" void kernel_launch(void* const* d_in, const int* in_sizes, int n_in,
                              void* d_out, int out_size, void* d_ws, size_t ws_size,
                              hipStream_t stream) {
    const float* unary = (const float*)d_in[0];  // [N][6]
    const float* feat  = (const float*)d_in[1];  // [N][3]
    const float* CM    = (const float*)d_in[2];  // [6][6]
    const float* LG    = (const float*)d_in[3];
    const float* SW    = (const float*)d_in[4];
    const float* BW    = (const float*)d_in[5];
    float* out = (float*)d_out;

    // fixed floats: norm_s,norm_b (2N) + pf (5N) + sm,tmpx,filt_s,msg (144N) + smbT (24N)
    const size_t fixed_f = (size_t)175 * NPIX;
    int js = 20;                                    // slice=320 (10 j-tiles of 32)
    if (ws_size < (fixed_f + (size_t)js * NPIX * CCP) * 4) js = 10;
    if (ws_size < (fixed_f + (size_t)js * NPIX * CCP) * 4) js = 5;
    if (ws_size < (fixed_f + (size_t)js * NPIX * CCP) * 4) js = 4;

    float* ws = (float*)d_ws;
    float* norm_s  = ws;                          // N
    float* norm_b  = norm_s + NPIX;               // N
    float* pf      = norm_b + NPIX;               // 5N (SoA)
    float* sm      = pf + (size_t)5 * NPIX;       // N*36 fp32
    float* tmpx    = sm + (size_t)NPIX * CC;      // N*36
    float* filt_s  = tmpx + (size_t)NPIX * CC;    // N*36
    float* msg     = filt_s + (size_t)NPIX * CC;  // N*36
    unsigned short* smbT = (unsigned short*)(msg + (size_t)NPIX * CC);  // 48 x N bf16
    float* part_b  = (float*)(smbT + (size_t)CCP * NPIX);               // js*N*48

    int bilblocks = 50 * js;

    k_init<<<25, 256, 0, stream>>>(unary, feat, sm, smbT, pf, norm_s);

    for (int it = 0; it < NUM_ITER; it++) {
        k_bil_convx<<<bilblocks + 900, 256, 0, stream>>>(smbT, pf, sm, part_b, tmpx,
                                                         js, bilblocks);
        k_convy<<<900, 256, 0, stream>>>(tmpx, filt_s);
        if (it == 0)
            k_update<true, false><<<150, 256, 0, stream>>>(part_b, filt_s, norm_s, norm_b,
                                                           unary, SW, BW, CM, LG,
                                                           sm, smbT, msg, js);
        else if (it < NUM_ITER - 1)
            k_update<false, false><<<150, 256, 0, stream>>>(part_b, filt_s, norm_s, norm_b,
                                                            unary, SW, BW, CM, LG,
                                                            sm, smbT, msg, js);
        else
            k_update<false, true><<<150, 256, 0, stream>>>(part_b, filt_s, norm_s, norm_b,
                                                           unary, SW, BW, CM, LG,
                                                           sm, smbT, msg, js);
    }

    hipMemsetAsync(out, 0, out_size * sizeof(float), stream);
    k_elbo<<<dim3(25, NC), 256, 0, stream>>>(sm, msg, unary, LG, out);
}

// Round 5
// 282.251 us; speedup vs baseline: 2.7653x; 1.1753x over previous
//
#include <hip/hip_runtime.h>
#include <hip/hip_bf16.h>
#include <math.h>

// Problem constants
#define HH 80
#define WW 80
#define NPIX 6400          // H*W
#define CC 36              // 6 labels x 6 channels
#define CCP 48             // padded: label l at channels l*8.. ; c==6 is ones->norm
#define NC 6
#define NUM_ITER 5
#define JS 10              // j-slices
#define SLICE (NPIX / JS)  // 640
#define JTILES (SLICE / 32)

typedef __attribute__((ext_vector_type(8))) short bfrag;   // 8 bf16 (4 VGPR)
typedef __attribute__((ext_vector_type(4))) float f32x4;   // MFMA acc

// coords prescaled so bilateral w = exp2(-(dy^2+dx^2+d0^2+d1^2+d2^2))
// spatial  w = exp2(-RS*(dy^2+dx^2)), RS = 128/18
__device__ __constant__ const float kSA = 0.08838834764831845f;  // sqrt(1/(128*ln2))
__device__ __constant__ const float kSB = 5.663898078577187f;    // sqrt(1/(0.045*ln2))
__device__ __constant__ const float kRS = 7.11111111f;           // 128/18

__device__ inline unsigned short f2bf(float f) {
    unsigned u = __builtin_bit_cast(unsigned, f);
    unsigned r = (u + 0x7FFFu + ((u >> 16) & 1u)) >> 16;
    return (unsigned short)r;
}

// ---------------------------------------------------------------------------
// init: pf SoA prescaled (y,x,f0,f1,f2); sm0 = softmax(unary) in fp32 [N][36]
// and bf16-transposed smbT [48][N] with rows l*8+6 = 1.0, l*8+7 = 0
// ---------------------------------------------------------------------------
__global__ __launch_bounds__(256) void k_init(const float* __restrict__ unary,
                                              const float* __restrict__ feat,
                                              float* __restrict__ sm,
                                              unsigned short* __restrict__ smbT,
                                              float* __restrict__ pf) {
    int i = blockIdx.x * 256 + threadIdx.x;
    if (i >= NPIX) return;
    int y = i / WW, x = i - y * WW;
    pf[0 * NPIX + i] = kSA * (float)y;
    pf[1 * NPIX + i] = kSA * (float)x;
    pf[2 * NPIX + i] = kSB * feat[i * 3 + 0];
    pf[3 * NPIX + i] = kSB * feat[i * 3 + 1];
    pf[4 * NPIX + i] = kSB * feat[i * 3 + 2];
    float v[NC], mx = -1e30f;
#pragma unroll
    for (int c = 0; c < NC; c++) { v[c] = unary[i * NC + c]; mx = fmaxf(mx, v[c]); }
    float sum = 0.f;
#pragma unroll
    for (int c = 0; c < NC; c++) { v[c] = __expf(v[c] - mx); sum += v[c]; }
    float inv = 1.f / sum;
#pragma unroll
    for (int l = 0; l < NC; l++) {
#pragma unroll
        for (int c = 0; c < NC; c++) {
            float s = v[c] * inv;
            sm[(size_t)i * CC + l * NC + c] = s;
            smbT[(size_t)(l * 8 + c) * NPIX + i] = f2bf(s);
        }
        smbT[(size_t)(l * 8 + 6) * NPIX + i] = 0x3F80;  // ones -> normalizer
        smbT[(size_t)(l * 8 + 7) * NPIX + i] = 0;
    }
}

// ---------------------------------------------------------------------------
// N^2 MFMA pass computing BOTH kernels against the same B (smbT) fragments.
// Block: 4 waves; wave owns 2 i-tiles (32 i); loops j over its slice.
// part_b / part_s [s][i][48] fp32; channels l*8+6 accumulate normalizers.
// A layout: row = lane&15, k = 8*(lane>>4)+e ; B: col = lane&15, same k;
// D: col = lane&15, row = 4*(lane>>4)+reg   (verified passing in round 4)
// ---------------------------------------------------------------------------
__global__ __launch_bounds__(256) void k_bil(const unsigned short* __restrict__ smbT,
                                             const float* __restrict__ pf,
                                             float* __restrict__ part_b,
                                             float* __restrict__ part_s) {
    int tid = threadIdx.x, bid = blockIdx.x;
    int s = bid / 50, ib = bid - s * 50;
    int j00 = s * SLICE;
    int wv = tid >> 6, lane = tid & 63, r = lane & 15, gq = lane >> 4;
    int it0 = ib * 128 + wv * 32;
    int iA = it0 + r, iB = iA + 16;

    const float* py = pf;
    const float* px = pf + NPIX;
    const float* p0 = pf + 2 * NPIX;
    const float* p1 = pf + 3 * NPIX;
    const float* p2 = pf + 4 * NPIX;

    float yA = py[iA], xA = px[iA], fA0 = p0[iA], fA1 = p1[iA], fA2 = p2[iA];
    float yB = py[iB], xB = px[iB], fB0 = p0[iB], fB1 = p1[iB], fB2 = p2[iB];

    f32x4 aAb[3], aBb[3], aAs[3], aBs[3];
#pragma unroll
    for (int t = 0; t < 3; t++) {
        aAb[t] = (f32x4){0.f, 0.f, 0.f, 0.f};
        aBb[t] = (f32x4){0.f, 0.f, 0.f, 0.f};
        aAs[t] = (f32x4){0.f, 0.f, 0.f, 0.f};
        aBs[t] = (f32x4){0.f, 0.f, 0.f, 0.f};
    }

    for (int jt = 0; jt < JTILES; jt++) {
        int jb = j00 + jt * 32 + 8 * gq;   // this lane's k-base
        f32x4 yj0 = *(const f32x4*)(py + jb), yj1 = *(const f32x4*)(py + jb + 4);
        f32x4 xj0 = *(const f32x4*)(px + jb), xj1 = *(const f32x4*)(px + jb + 4);
        f32x4 c00 = *(const f32x4*)(p0 + jb), c01 = *(const f32x4*)(p0 + jb + 4);
        f32x4 c10 = *(const f32x4*)(p1 + jb), c11 = *(const f32x4*)(p1 + jb + 4);
        f32x4 c20 = *(const f32x4*)(p2 + jb), c21 = *(const f32x4*)(p2 + jb + 4);
        bfrag Bf[3];
#pragma unroll
        for (int t = 0; t < 3; t++)
            Bf[t] = *(const bfrag*)(smbT + (size_t)(16 * t + r) * NPIX + jb);

        float wAb[8], wAs[8], wBb[8], wBs[8];
#pragma unroll
        for (int e = 0; e < 8; e++) {
            float yj = (e < 4) ? yj0[e & 3] : yj1[e & 3];
            float xj = (e < 4) ? xj0[e & 3] : xj1[e & 3];
            float u0 = (e < 4) ? c00[e & 3] : c01[e & 3];
            float u1 = (e < 4) ? c10[e & 3] : c11[e & 3];
            float u2 = (e < 4) ? c20[e & 3] : c21[e & 3];
            float dy = yA - yj, dx = xA - xj;
            float sp = dy * dy; sp = fmaf(dx, dx, sp);
            float d0 = fA0 - u0, d1 = fA1 - u1, d2 = fA2 - u2;
            float ab = fmaf(d0, d0, sp); ab = fmaf(d1, d1, ab); ab = fmaf(d2, d2, ab);
            wAb[e] = __builtin_amdgcn_exp2f(-ab);
            wAs[e] = __builtin_amdgcn_exp2f(-kRS * sp);
            dy = yB - yj; dx = xB - xj;
            sp = dy * dy; sp = fmaf(dx, dx, sp);
            d0 = fB0 - u0; d1 = fB1 - u1; d2 = fB2 - u2;
            ab = fmaf(d0, d0, sp); ab = fmaf(d1, d1, ab); ab = fmaf(d2, d2, ab);
            wBb[e] = __builtin_amdgcn_exp2f(-ab);
            wBs[e] = __builtin_amdgcn_exp2f(-kRS * sp);
        }
        union { unsigned u[4]; bfrag v; } Ab, As, Bb, Bs;
#pragma unroll
        for (int m = 0; m < 4; m++) {
            asm("v_cvt_pk_bf16_f32 %0, %1, %2" : "=v"(Ab.u[m]) : "v"(wAb[2 * m]), "v"(wAb[2 * m + 1]));
            asm("v_cvt_pk_bf16_f32 %0, %1, %2" : "=v"(As.u[m]) : "v"(wAs[2 * m]), "v"(wAs[2 * m + 1]));
            asm("v_cvt_pk_bf16_f32 %0, %1, %2" : "=v"(Bb.u[m]) : "v"(wBb[2 * m]), "v"(wBb[2 * m + 1]));
            asm("v_cvt_pk_bf16_f32 %0, %1, %2" : "=v"(Bs.u[m]) : "v"(wBs[2 * m]), "v"(wBs[2 * m + 1]));
        }
#pragma unroll
        for (int t = 0; t < 3; t++) {
            aAb[t] = __builtin_amdgcn_mfma_f32_16x16x32_bf16(Ab.v, Bf[t], aAb[t], 0, 0, 0);
            aAs[t] = __builtin_amdgcn_mfma_f32_16x16x32_bf16(As.v, Bf[t], aAs[t], 0, 0, 0);
            aBb[t] = __builtin_amdgcn_mfma_f32_16x16x32_bf16(Bb.v, Bf[t], aBb[t], 0, 0, 0);
            aBs[t] = __builtin_amdgcn_mfma_f32_16x16x32_bf16(Bs.v, Bf[t], aBs[t], 0, 0, 0);
        }
    }
#pragma unroll
    for (int t = 0; t < 3; t++)
#pragma unroll
        for (int d = 0; d < 4; d++) {
            int irow = it0 + 4 * gq + d;
            size_t o1 = ((size_t)s * NPIX + irow) * CCP + 16 * t + r;
            size_t o2 = ((size_t)s * NPIX + irow + 16) * CCP + 16 * t + r;
            part_b[o1] = aAb[t][d];
            part_b[o2] = aBb[t][d];
            part_s[o1] = aAs[t][d];
            part_s[o2] = aBs[t][d];
        }
}

// ---------------------------------------------------------------------------
// update: reduce parts (norm = channel l*8+6), message, pairwise, q, softmax.
// LAST: compute ELBO partial sums directly into out[6] (no sm/q write).
// Grid is exactly 150*256 == NPIX*NC (no early returns; safe __syncthreads).
// ---------------------------------------------------------------------------
template <bool LAST>
__global__ __launch_bounds__(256) void k_update(const float* __restrict__ part_b,
                                                const float* __restrict__ part_s,
                                                const float* __restrict__ unary,
                                                const float* __restrict__ SW,
                                                const float* __restrict__ BW,
                                                const float* __restrict__ CM,
                                                const float* __restrict__ LG,
                                                float* __restrict__ sm,
                                                unsigned short* __restrict__ smbT,
                                                float* __restrict__ out) {
    __shared__ float sSW[36], sBW[36], sCM[36], sLG[36];
    __shared__ float bins[NC];
    int tid = threadIdx.x;
    if (tid < 36) { sSW[tid] = SW[tid]; sBW[tid] = BW[tid]; sCM[tid] = CM[tid]; sLG[tid] = LG[tid]; }
    if (LAST && tid < NC) bins[tid] = 0.f;
    __syncthreads();
    int t = blockIdx.x * 256 + tid;  // t = n*6 + l
    int n = t / NC, l = t - n * NC;

    float fb[NC], fs[NC], nb = 0.f, ns = 0.f;
#pragma unroll
    for (int c = 0; c < NC; c++) { fb[c] = 0.f; fs[c] = 0.f; }
    for (int s = 0; s < JS; s++) {
        const float4* pb = (const float4*)(part_b + ((size_t)s * NPIX + n) * CCP + l * 8);
        const float4* ps = (const float4*)(part_s + ((size_t)s * NPIX + n) * CCP + l * 8);
        float4 b0 = pb[0], b1 = pb[1];
        float4 s0 = ps[0], s1 = ps[1];
        fb[0] += b0.x; fb[1] += b0.y; fb[2] += b0.z; fb[3] += b0.w;
        fb[4] += b1.x; fb[5] += b1.y; nb += b1.z;
        fs[0] += s0.x; fs[1] += s0.y; fs[2] += s0.z; fs[3] += s0.w;
        fs[4] += s1.x; fs[5] += s1.y; ns += s1.z;
    }
    float invb = 1.f / nb, invs = 1.f / ns;
#pragma unroll
    for (int c = 0; c < NC; c++) { fb[c] *= invb; fs[c] *= invs; }

    float m[NC];
#pragma unroll
    for (int c = 0; c < NC; c++) {
        float a = 0.f;
#pragma unroll
        for (int cp = 0; cp < NC; cp++)
            a += sSW[c * NC + cp] * fs[cp] + sBW[c * NC + cp] * fb[cp];
        m[c] = a;
    }
    const float* up = unary + (size_t)n * NC;
    if (!LAST) {
        float qv[NC], mxq = -1e30f;
#pragma unroll
        for (int c = 0; c < NC; c++) {
            float pw = 0.f;
#pragma unroll
            for (int cp = 0; cp < NC; cp++) pw += sCM[c * NC + cp] * m[cp];
            qv[c] = up[c] + sLG[c * NC + l] - pw;
            mxq = fmaxf(mxq, qv[c]);
        }
        float e[NC], ssum = 0.f;
#pragma unroll
        for (int c = 0; c < NC; c++) { e[c] = __expf(qv[c] - mxq); ssum += e[c]; }
        float inv = 1.f / ssum;
        float* sp = sm + (size_t)n * CC + l * NC;
#pragma unroll
        for (int c = 0; c < NC; c++) {
            float sv = e[c] * inv;
            sp[c] = sv;
            smbT[(size_t)(l * 8 + c) * NPIX + n] = f2bf(sv);
        }
    } else {
        const float* sp = sm + (size_t)n * CC + l * NC;
        float v = 0.f;
#pragma unroll
        for (int c = 0; c < NC; c++) {
            float sv = sp[c];
            v += sv * (up[c] + sLG[c * NC + l] - logf(sv + 1e-10f) - m[c]);
        }
        atomicAdd(&bins[l], v);
        __syncthreads();
        if (tid < NC) atomicAdd(&out[tid], bins[tid]);
    }
}

// ---------------------------------------------------------------------------
extern "C" void kernel_launch(void* const* d_in, const int* in_sizes, int n_in,
                              void* d_out, int out_size, void* d_ws, size_t ws_size,
                              hipStream_t stream) {
    const float* unary = (const float*)d_in[0];  // [N][6]
    const float* feat  = (const float*)d_in[1];  // [N][3]
    const float* CM    = (const float*)d_in[2];  // [6][6]
    const float* LG    = (const float*)d_in[3];
    const float* SW    = (const float*)d_in[4];
    const float* BW    = (const float*)d_in[5];
    float* out = (float*)d_out;

    float* ws = (float*)d_ws;
    float* pf = ws;                                     // 5N
    float* sm = pf + (size_t)5 * NPIX;                  // 36N fp32
    unsigned short* smbT = (unsigned short*)(sm + (size_t)CC * NPIX);  // 48 x N bf16
    float* part_b = sm + (size_t)(CC + 24) * NPIX;      // JS*N*48
    float* part_s = part_b + (size_t)JS * NPIX * CCP;   // JS*N*48

    hipMemsetAsync(out, 0, out_size * sizeof(float), stream);
    k_init<<<25, 256, 0, stream>>>(unary, feat, sm, smbT, pf);

    for (int it = 0; it < NUM_ITER; it++) {
        k_bil<<<JS * 50, 256, 0, stream>>>(smbT, pf, part_b, part_s);
        if (it < NUM_ITER - 1)
            k_update<false><<<150, 256, 0, stream>>>(part_b, part_s, unary,
                                                     SW, BW, CM, LG, sm, smbT, out);
        else
            k_update<true><<<150, 256, 0, stream>>>(part_b, part_s, unary,
                                                    SW, BW, CM, LG, sm, smbT, out);
    }
}